// Round 6
// baseline (526.361 us; speedup 1.0000x reference)
//
#include <hip/hip_runtime.h>
#include <math.h>

#define NB 4
#define C_ 256
#define NG 8
#define CPG 32
#define HW 4096
#define NH 4
#define HD 64
#define EPS 1e-5f
#define QSCALE 0.1803368801111204f  /* 0.125 * log2(e): folds 1/sqrt(64) and base-2 softmax */

typedef __attribute__((ext_vector_type(8))) short bf16x8_t;
typedef __attribute__((ext_vector_type(4))) float f32x4_t;

__device__ __forceinline__ unsigned short f2bf(float f) {
    unsigned u = __float_as_uint(f);
    u += 0x7FFFu + ((u >> 16) & 1u);   // RNE
    return (unsigned short)(u >> 16);
}

// ---------------- GroupNorm stats: one block per (b,g); group data is contiguous ----------------
__global__ __launch_bounds__(256) void gn_stats_k(const float* __restrict__ x,
                                                  float* __restrict__ stats) {
    int bg = blockIdx.x;  // 0..31
    const float4* base = (const float4*)(x + (size_t)bg * CPG * HW);
    const int n4 = CPG * HW / 4;  // 32768
    float s = 0.f, ss = 0.f;
    for (int i = threadIdx.x; i < n4; i += 256) {
        float4 v = base[i];
        s  += v.x + v.y + v.z + v.w;
        ss += v.x*v.x + v.y*v.y + v.z*v.z + v.w*v.w;
    }
    #pragma unroll
    for (int off = 32; off > 0; off >>= 1) {
        s  += __shfl_down(s, off);
        ss += __shfl_down(ss, off);
    }
    __shared__ float rs[4], rss[4];
    int wv = threadIdx.x >> 6;
    if ((threadIdx.x & 63) == 0) { rs[wv] = s; rss[wv] = ss; }
    __syncthreads();
    if (threadIdx.x == 0) {
        float S  = rs[0] + rs[1] + rs[2] + rs[3];
        float SS = rss[0] + rss[1] + rss[2] + rss[3];
        const float inv = 1.f / (float)(CPG * HW);
        float mean = S * inv;
        float var  = SS * inv - mean * mean;
        stats[2*bg]   = mean;
        stats[2*bg+1] = rsqrtf(var + EPS);
    }
}

// ---------------- GroupNorm apply (elementwise, float4) ----------------
__global__ __launch_bounds__(256) void gn_apply_k(const float* __restrict__ x,
                                                  const float* __restrict__ gamma,
                                                  const float* __restrict__ beta,
                                                  const float* __restrict__ stats,
                                                  float* __restrict__ h) {
    int idx = blockIdx.x * 256 + threadIdx.x;     // float4 index
    int bc = idx / (HW / 4);                       // b*256+c
    int b = bc >> 8, c = bc & 255;
    int bg = b * NG + (c >> 5);
    float mean = stats[2*bg], rstd = stats[2*bg+1];
    float sc = gamma[c] * rstd;
    float sh = beta[c] - mean * sc;
    float4 v = ((const float4*)x)[idx];
    float4 o;
    o.x = v.x*sc + sh; o.y = v.y*sc + sh; o.z = v.z*sc + sh; o.w = v.w*sc + sh;
    ((float4*)h)[idx] = o;
}

// ---------------- fp32 GEMM (used for proj): out[b][m][p] = A[m][:]·Bm[b][:][p] + bias[m] (+resid) ----------------
__global__ __launch_bounds__(256) void gemm_k(const float* __restrict__ A,
                                              const float* __restrict__ Bm,
                                              const float* __restrict__ bias,
                                              const float* __restrict__ resid,
                                              float* __restrict__ out,
                                              int Mdim) {
    __shared__ float Ast[16][68];
    __shared__ float Bs[16][68];
    int b  = blockIdx.z;
    int my = blockIdx.y;
    int nx = blockIdx.x;
    int t = threadIdx.x;
    int ty = t >> 4, tx = t & 15;
    const float* Ab = A + (size_t)my * 64 * 256;
    const float* Bb = Bm + (size_t)b * 256 * HW + nx * 64;
    float acc[4][4] = {};
    int lr  = t >> 2;
    int lc  = (t & 3) * 4;
    int brr = t >> 4;
    int bc4 = (t & 15) * 4;
    for (int k0 = 0; k0 < 256; k0 += 16) {
        float4 av = *(const float4*)(Ab + lr * 256 + k0 + lc);
        float4 bv = *(const float4*)(Bb + (size_t)(k0 + brr) * HW + bc4);
        Ast[lc + 0][lr] = av.x;
        Ast[lc + 1][lr] = av.y;
        Ast[lc + 2][lr] = av.z;
        Ast[lc + 3][lr] = av.w;
        *(float4*)&Bs[brr][bc4] = bv;
        __syncthreads();
        #pragma unroll
        for (int kk = 0; kk < 16; kk++) {
            float4 a4 = *(const float4*)&Ast[kk][ty * 4];
            float4 b4 = *(const float4*)&Bs[kk][tx * 4];
            acc[0][0] += a4.x*b4.x; acc[0][1] += a4.x*b4.y; acc[0][2] += a4.x*b4.z; acc[0][3] += a4.x*b4.w;
            acc[1][0] += a4.y*b4.x; acc[1][1] += a4.y*b4.y; acc[1][2] += a4.y*b4.z; acc[1][3] += a4.y*b4.w;
            acc[2][0] += a4.z*b4.x; acc[2][1] += a4.z*b4.y; acc[2][2] += a4.z*b4.z; acc[2][3] += a4.z*b4.w;
            acc[3][0] += a4.w*b4.x; acc[3][1] += a4.w*b4.y; acc[3][2] += a4.w*b4.z; acc[3][3] += a4.w*b4.w;
        }
        __syncthreads();
    }
    #pragma unroll
    for (int r = 0; r < 4; r++) {
        int m = my * 64 + ty * 4 + r;
        size_t off = ((size_t)b * Mdim + m) * HW + nx * 64 + tx * 4;
        float bsv = bias[m];
        float4 o;
        o.x = acc[r][0] + bsv; o.y = acc[r][1] + bsv; o.z = acc[r][2] + bsv; o.w = acc[r][3] + bsv;
        if (resid != nullptr) {
            float4 rv = *(const float4*)(resid + off);
            o.x += rv.x; o.y += rv.y; o.z += rv.z; o.w += rv.w;
        }
        *(float4*)(out + off) = o;
    }
}

// ---------------- QKV GEMM (fp32 math) with bf16 multi-layout epilogue ----------------
// my 0..3: Q head my  -> qt[(b,h)][p][d] bf16, scaled by QSCALE (transposed via LDS)
// my 4..7: K head my-4-> kt[(b,h)][p][d] bf16 (transposed via LDS)
// my 8..11:V head my-8-> vv[(b,h)][d][p] bf16 (direct)
__global__ __launch_bounds__(256) void gemm_qkv_k(const float* __restrict__ A,     // w_qkv [768][256]
                                                  const float* __restrict__ Bm,    // h [NB][256][HW]
                                                  const float* __restrict__ bias,  // [768]
                                                  unsigned short* __restrict__ qt,
                                                  unsigned short* __restrict__ kt,
                                                  unsigned short* __restrict__ vv) {
    __shared__ float Ast[16][68];
    __shared__ float Bs[16][68];
    __shared__ unsigned short T[64][72];   // [p][d] staging, 144B rows (16B aligned)
    int b  = blockIdx.z;
    int my = blockIdx.y;   // 0..11
    int nx = blockIdx.x;
    int t = threadIdx.x;
    int ty = t >> 4, tx = t & 15;
    const float* Ab = A + (size_t)my * 64 * 256;
    const float* Bb = Bm + (size_t)b * 256 * HW + nx * 64;
    float acc[4][4] = {};
    int lr  = t >> 2;
    int lc  = (t & 3) * 4;
    int brr = t >> 4;
    int bc4 = (t & 15) * 4;
    for (int k0 = 0; k0 < 256; k0 += 16) {
        float4 av = *(const float4*)(Ab + lr * 256 + k0 + lc);
        float4 bv = *(const float4*)(Bb + (size_t)(k0 + brr) * HW + bc4);
        Ast[lc + 0][lr] = av.x;
        Ast[lc + 1][lr] = av.y;
        Ast[lc + 2][lr] = av.z;
        Ast[lc + 3][lr] = av.w;
        *(float4*)&Bs[brr][bc4] = bv;
        __syncthreads();
        #pragma unroll
        for (int kk = 0; kk < 16; kk++) {
            float4 a4 = *(const float4*)&Ast[kk][ty * 4];
            float4 b4 = *(const float4*)&Bs[kk][tx * 4];
            acc[0][0] += a4.x*b4.x; acc[0][1] += a4.x*b4.y; acc[0][2] += a4.x*b4.z; acc[0][3] += a4.x*b4.w;
            acc[1][0] += a4.y*b4.x; acc[1][1] += a4.y*b4.y; acc[1][2] += a4.y*b4.z; acc[1][3] += a4.y*b4.w;
            acc[2][0] += a4.z*b4.x; acc[2][1] += a4.z*b4.y; acc[2][2] += a4.z*b4.z; acc[2][3] += a4.z*b4.w;
            acc[3][0] += a4.w*b4.x; acc[3][1] += a4.w*b4.y; acc[3][2] += a4.w*b4.z; acc[3][3] += a4.w*b4.w;
        }
        __syncthreads();
    }
    int sec = my >> 2;        // 0=q, 1=k, 2=v
    int hh  = my & 3;
    if (sec == 2) {
        // V: direct [d][p] bf16 store
        #pragma unroll
        for (int r = 0; r < 4; r++) {
            int d = ty * 4 + r;
            float bsv = bias[my * 64 + d];
            size_t off = ((size_t)(b * NH + hh) * 64 + d) * HW + nx * 64 + tx * 4;
            ushort4 o;
            o.x = f2bf(acc[r][0] + bsv); o.y = f2bf(acc[r][1] + bsv);
            o.z = f2bf(acc[r][2] + bsv); o.w = f2bf(acc[r][3] + bsv);
            *(ushort4*)(vv + off) = o;
        }
    } else {
        // Q/K: transpose through LDS -> [p][d] bf16
        float sc = (sec == 0) ? QSCALE : 1.f;
        #pragma unroll
        for (int r = 0; r < 4; r++) {
            float bsv = bias[my * 64 + ty * 4 + r];
            #pragma unroll
            for (int c = 0; c < 4; c++)
                T[tx * 4 + c][ty * 4 + r] = f2bf((acc[r][c] + bsv) * sc);
        }
        __syncthreads();
        unsigned short* dst = ((sec == 0) ? qt : kt) + ((size_t)(b * NH + hh) * HW + nx * 64) * 64;
        int p = t >> 2, cc = t & 3;
        *(uint4*)(dst + p * 64 + cc * 16)     = *(const uint4*)&T[p][cc * 16];
        *(uint4*)(dst + p * 64 + cc * 16 + 8) = *(const uint4*)&T[p][cc * 16 + 8];
    }
}

// ---------------- Flash attention, bf16 MFMA, i×j wave split ----------------
// qt,kt: [(b,h)][p][64] bf16 (Q pre-scaled by QSCALE); vv: [(b,h)][64][p] bf16.
// Block: 64-query tile, 4 waves = 2 i-halves (iw) x 2 j-halves (jw); per-wave 32i x 32j
// of every 64-j tile with its own online-softmax state; j-halves merged in epilogue.
// S^T = K·Q^T orientation (softmax per-lane-replicated, 2 shuffles per reduce).
// LDS 24KB -> up to 6 blocks/CU.
// __launch_bounds__(256) ONE-ARG ONLY: r5's (256,4) forced a 128-reg unified
// VGPR+AGPR cap -> allocator spilled the K-loop working set to scratch
// (WRITE_SIZE 28MB -> 700MB, VGPR 80->60, dur 242->314us). Natural allocation
// (~90-110 regs) gives 4-6 waves/EU without spilling. [r5 post-mortem]
__global__ __launch_bounds__(256) void attn_k(const unsigned short* __restrict__ qt,
                                              const unsigned short* __restrict__ kt,
                                              const unsigned short* __restrict__ vv,
                                              float* __restrict__ attno) {
    __shared__ __align__(16) unsigned short smem[12288];  // 24KB: K | V | P
    unsigned short* Klds = smem;          // 64 rows(j) x 64(d), swizzled 16B chunks
    unsigned short* Vlds = smem + 4096;   // 64 rows(d) x 64(j), swizzled
    unsigned short* Pt   = smem + 8192;   // [wave][mi][chunk 0..63][8] fragment-ready, 8KB
    int t = threadIdx.x;
    int wave = t >> 6, lane = t & 63, quad = lane >> 4, l16 = lane & 15;
    int iw = wave & 1, jw = wave >> 1;
    int i0 = blockIdx.x * 64;
    int hh = blockIdx.y, b = blockIdx.z;
    const unsigned short* qb  = qt + (size_t)(b * NH + hh) * HW * 64;
    const unsigned short* kbp = kt + (size_t)(b * NH + hh) * HW * 64;
    const unsigned short* vbp = vv + (size_t)(b * NH + hh) * 64 * HW;

    // Q B-frags: lane holds Q[i = i0+iw*32+mi*16+l16][d = kc*32+quad*8 ..+8]
    bf16x8_t qf[2][2];
    #pragma unroll
    for (int mi = 0; mi < 2; mi++)
        #pragma unroll
        for (int kc = 0; kc < 2; kc++)
            qf[mi][kc] = *(const bf16x8_t*)(qb + (size_t)(i0 + iw * 32 + mi * 16 + l16) * 64 + kc * 32 + quad * 8);

    f32x4_t oacc[4][2];
    const f32x4_t zz = {0.f, 0.f, 0.f, 0.f};
    #pragma unroll
    for (int dt = 0; dt < 4; dt++) { oacc[dt][0] = zz; oacc[dt][1] = zz; }
    float m_pr[2] = {-INFINITY, -INFINITY};
    float l_sum[2] = {0.f, 0.f};

    // staging maps (constant per thread)
    int soffK[2], soffV[2], slds[2];
    #pragma unroll
    for (int n = 0; n < 2; n++) {
        int s = n * 256 + t;
        int row = s >> 3;
        int c = (s & 7) ^ (row & 7);
        soffK[n] = row * 128 + c * 16;          // bytes (row=j, 128B rows)
        soffV[n] = row * (HW * 2) + c * 16;     // bytes (row=d, stride HW*2)
        slds[n] = s * 8;                        // ushort index
    }
    uint4 kreg[2], vreg[2];
    {
        const char* kbase = (const char*)kbp;
        const char* vbase = (const char*)vbp;
        kreg[0] = *(const uint4*)(kbase + soffK[0]); kreg[1] = *(const uint4*)(kbase + soffK[1]);
        vreg[0] = *(const uint4*)(vbase + soffV[0]); vreg[1] = *(const uint4*)(vbase + soffV[1]);
    }

    for (int jt = 0; jt < 64; jt++) {
        __syncthreads();   // previous tile fully consumed
        *(uint4*)&Klds[slds[0]] = kreg[0]; *(uint4*)&Klds[slds[1]] = kreg[1];
        *(uint4*)&Vlds[slds[0]] = vreg[0]; *(uint4*)&Vlds[slds[1]] = vreg[1];
        __syncthreads();   // tiles ready
        if (jt < 63) {     // prefetch next tile into regs
            const char* kbase = (const char*)kbp + (size_t)(jt + 1) * 8192;
            const char* vbase = (const char*)vbp + (size_t)(jt + 1) * 128;
            kreg[0] = *(const uint4*)(kbase + soffK[0]); kreg[1] = *(const uint4*)(kbase + soffK[1]);
            vreg[0] = *(const uint4*)(vbase + soffV[0]); vreg[1] = *(const uint4*)(vbase + soffV[1]);
        }

        // ---- S^T = K·Q^T on this wave's 32 j x 32 i ----
        f32x4_t sacc[2][2];
        sacc[0][0] = zz; sacc[0][1] = zz; sacc[1][0] = zz; sacc[1][1] = zz;
        #pragma unroll
        for (int nj = 0; nj < 2; nj++) {
            int j = jw * 32 + nj * 16 + l16;        // A-operand row
            int rb = j * 8;
            bf16x8_t kf0 = *(const bf16x8_t*)&Klds[(rb + ((quad    ) ^ (j & 7))) * 8];
            bf16x8_t kf1 = *(const bf16x8_t*)&Klds[(rb + ((4 + quad) ^ (j & 7))) * 8];
            #pragma unroll
            for (int mi = 0; mi < 2; mi++) {
                sacc[mi][nj] = __builtin_amdgcn_mfma_f32_16x16x32_bf16(kf0, qf[mi][0], sacc[mi][nj], 0, 0, 0);
                sacc[mi][nj] = __builtin_amdgcn_mfma_f32_16x16x32_bf16(kf1, qf[mi][1], sacc[mi][nj], 0, 0, 0);
            }
        }

        // ---- online softmax (base-2) per i-tile; state per-lane-replicated, j-half-local ----
        float alpha_[2];
        #pragma unroll
        for (int mi = 0; mi < 2; mi++) {
            float m = sacc[mi][0][0];
            #pragma unroll
            for (int nj = 0; nj < 2; nj++)
                #pragma unroll
                for (int r = 0; r < 4; r++) m = fmaxf(m, sacc[mi][nj][r]);
            m = fmaxf(m, __shfl_xor(m, 16));
            m = fmaxf(m, __shfl_xor(m, 32));
            float mnew = fmaxf(m_pr[mi], m);
            float a = __builtin_amdgcn_exp2f(m_pr[mi] - mnew);
            alpha_[mi] = a;
            float rs = 0.f;
            #pragma unroll
            for (int nj = 0; nj < 2; nj++)
                #pragma unroll
                for (int r = 0; r < 4; r++) {
                    float p = __builtin_amdgcn_exp2f(sacc[mi][nj][r] - mnew);
                    sacc[mi][nj][r] = p;
                    rs += p;
                }
            rs += __shfl_xor(rs, 16);
            rs += __shfl_xor(rs, 32);
            l_sum[mi] = l_sum[mi] * a + rs;
            m_pr[mi] = mnew;

            // P -> wave-private LDS, fragment-ready: writer (quad,l16) holds
            // P[j' = nj*16+quad*4+r][i' = mi*16+l16]; reader chunk = rq*16+l16 with
            // j' = rq*8+idx  =>  rq = nj*2+(quad>>1), halfword off 4*(quad&1).
            #pragma unroll
            for (int nj = 0; nj < 2; nj++) {
                unsigned lo = (unsigned)f2bf(sacc[mi][nj][0]) | ((unsigned)f2bf(sacc[mi][nj][1]) << 16);
                unsigned hi = (unsigned)f2bf(sacc[mi][nj][2]) | ((unsigned)f2bf(sacc[mi][nj][3]) << 16);
                int chunk = (nj * 2 + (quad >> 1)) * 16 + l16;
                *(uint2*)&Pt[((wave * 2 + mi) * 64 + chunk) * 8 + 4 * (quad & 1)] = make_uint2(lo, hi);
            }
        }

        // rescale O by alpha (registers only)
        #pragma unroll
        for (int dt = 0; dt < 4; dt++) { oacc[dt][0] *= alpha_[0]; oacc[dt][1] *= alpha_[1]; }

        __threadfence_block();   // wave-private P round-trip: fence compiler + lgkm (r2 lesson)

        // ---- PV: O^T[d][i] += V[d][j-half]·P[j-half][i], K-dim = this wave's 32 j ----
        bf16x8_t pf[2];
        pf[0] = *(const bf16x8_t*)&Pt[((wave * 2 + 0) * 64 + quad * 16 + l16) * 8];
        pf[1] = *(const bf16x8_t*)&Pt[((wave * 2 + 1) * 64 + quad * 16 + l16) * 8];
        #pragma unroll
        for (int dt = 0; dt < 4; dt++) {
            int d = dt * 16 + l16;
            bf16x8_t vf = *(const bf16x8_t*)&Vlds[(d * 8 + ((jw * 4 + quad) ^ (d & 7))) * 8];
            oacc[dt][0] = __builtin_amdgcn_mfma_f32_16x16x32_bf16(vf, pf[0], oacc[dt][0], 0, 0, 0);
            oacc[dt][1] = __builtin_amdgcn_mfma_f32_16x16x32_bf16(vf, pf[1], oacc[dt][1], 0, 0, 0);
        }
    }

    // ---- epilogue: merge the two j-halves (split-k flash rescale), write O^T fp32 ----
    __syncthreads();                       // all K/V/P consumption done; reuse smem
    float* Obuf = (float*)smem;            // [iw][64 d][32 i'] = 16KB
    float2* ml  = (float2*)Pt;             // [iw][32 i'] (m, l)
    if (jw == 0) {
        #pragma unroll
        for (int dt = 0; dt < 4; dt++)
            #pragma unroll
            for (int mi = 0; mi < 2; mi++)
                #pragma unroll
                for (int r = 0; r < 4; r++)
                    Obuf[iw * 2048 + (dt * 16 + quad * 4 + r) * 32 + mi * 16 + l16] = oacc[dt][mi][r];
        if (quad == 0) {
            ml[iw * 32 + l16]      = make_float2(m_pr[0], l_sum[0]);
            ml[iw * 32 + 16 + l16] = make_float2(m_pr[1], l_sum[1]);
        }
    }
    __syncthreads();
    if (jw == 1) {
        float c0[2], c1[2];
        #pragma unroll
        for (int mi = 0; mi < 2; mi++) {
            float2 s0 = ml[iw * 32 + mi * 16 + l16];
            float mm = fmaxf(s0.x, m_pr[mi]);
            float a0 = __builtin_amdgcn_exp2f(s0.x - mm);
            float a1 = __builtin_amdgcn_exp2f(m_pr[mi] - mm);
            float l  = s0.y * a0 + l_sum[mi] * a1;
            c0[mi] = a0 / l; c1[mi] = a1 / l;
        }
        float* ob = attno + (size_t)(b * NH + hh) * 64 * HW + i0 + iw * 32;
        #pragma unroll
        for (int dt = 0; dt < 4; dt++)
            #pragma unroll
            for (int mi = 0; mi < 2; mi++)
                #pragma unroll
                for (int r = 0; r < 4; r++) {
                    int d = dt * 16 + quad * 4 + r;
                    float v = Obuf[iw * 2048 + d * 32 + mi * 16 + l16] * c0[mi] + oacc[dt][mi][r] * c1[mi];
                    ob[(size_t)d * HW + mi * 16 + l16] = v;
                }
    }
}

extern "C" void kernel_launch(void* const* d_in, const int* in_sizes, int n_in,
                              void* d_out, int out_size, void* d_ws, size_t ws_size,
                              hipStream_t stream) {
    const float* x      = (const float*)d_in[0];
    const float* gamma  = (const float*)d_in[1];
    const float* beta   = (const float*)d_in[2];
    const float* w_qkv  = (const float*)d_in[3];
    const float* b_qkv  = (const float*)d_in[4];
    const float* w_proj = (const float*)d_in[5];
    const float* b_proj = (const float*)d_in[6];
    float* out = (float*)d_out;

    // ws: stats[256] | attno fp32 [4M] | qt bf16 [4M] | kt bf16 [4M] | vv bf16 [4M]  => ~41 MB
    float* stats = (float*)d_ws;
    float* attno = stats + 256;
    unsigned short* qt = (unsigned short*)(attno + (size_t)NB * C_ * HW);
    unsigned short* kt = qt + (size_t)NB * NH * HW * 64;
    unsigned short* vv = kt + (size_t)NB * NH * HW * 64;
    float* h = out;  // reuse d_out as GroupNorm output; consumed by gemm_qkv, overwritten by final GEMM

    gn_stats_k<<<32, 256, 0, stream>>>(x, stats);
    gn_apply_k<<<NB * C_ * HW / 4 / 256, 256, 0, stream>>>(x, gamma, beta, stats, h);
    gemm_qkv_k<<<dim3(HW / 64, 12, NB), 256, 0, stream>>>(w_qkv, h, b_qkv, qt, kt, vv);
    attn_k<<<dim3(HW / 64, NH, NB), 256, 0, stream>>>(qt, kt, vv, attno);
    gemm_k<<<dim3(HW / 64, 4, NB), 256, 0, stream>>>(w_proj, attno, b_proj, x, out, 256);
}

// Round 7
// 515.600 us; speedup vs baseline: 1.0209x; 1.0209x over previous
//
#include <hip/hip_runtime.h>
#include <math.h>

#define NB 4
#define C_ 256
#define NG 8
#define CPG 32
#define HW 4096
#define NH 4
#define HD 64
#define EPS 1e-5f
#define QSCALE 0.1803368801111204f  /* 0.125 * log2(e): folds 1/sqrt(64) and base-2 softmax */

typedef __attribute__((ext_vector_type(8))) short bf16x8_t;
typedef __attribute__((ext_vector_type(4))) float f32x4_t;

__device__ __forceinline__ unsigned short f2bf(float f) {
    unsigned u = __float_as_uint(f);
    u += 0x7FFFu + ((u >> 16) & 1u);   // RNE
    return (unsigned short)(u >> 16);
}

// ---------------- GroupNorm stats: one block per (b,g); group data is contiguous ----------------
__global__ __launch_bounds__(256) void gn_stats_k(const float* __restrict__ x,
                                                  float* __restrict__ stats) {
    int bg = blockIdx.x;  // 0..31
    const float4* base = (const float4*)(x + (size_t)bg * CPG * HW);
    const int n4 = CPG * HW / 4;  // 32768
    float s = 0.f, ss = 0.f;
    for (int i = threadIdx.x; i < n4; i += 256) {
        float4 v = base[i];
        s  += v.x + v.y + v.z + v.w;
        ss += v.x*v.x + v.y*v.y + v.z*v.z + v.w*v.w;
    }
    #pragma unroll
    for (int off = 32; off > 0; off >>= 1) {
        s  += __shfl_down(s, off);
        ss += __shfl_down(ss, off);
    }
    __shared__ float rs[4], rss[4];
    int wv = threadIdx.x >> 6;
    if ((threadIdx.x & 63) == 0) { rs[wv] = s; rss[wv] = ss; }
    __syncthreads();
    if (threadIdx.x == 0) {
        float S  = rs[0] + rs[1] + rs[2] + rs[3];
        float SS = rss[0] + rss[1] + rss[2] + rss[3];
        const float inv = 1.f / (float)(CPG * HW);
        float mean = S * inv;
        float var  = SS * inv - mean * mean;
        stats[2*bg]   = mean;
        stats[2*bg+1] = rsqrtf(var + EPS);
    }
}

// ---------------- GroupNorm apply (elementwise, float4) ----------------
__global__ __launch_bounds__(256) void gn_apply_k(const float* __restrict__ x,
                                                  const float* __restrict__ gamma,
                                                  const float* __restrict__ beta,
                                                  const float* __restrict__ stats,
                                                  float* __restrict__ h) {
    int idx = blockIdx.x * 256 + threadIdx.x;     // float4 index
    int bc = idx / (HW / 4);                       // b*256+c
    int b = bc >> 8, c = bc & 255;
    int bg = b * NG + (c >> 5);
    float mean = stats[2*bg], rstd = stats[2*bg+1];
    float sc = gamma[c] * rstd;
    float sh = beta[c] - mean * sc;
    float4 v = ((const float4*)x)[idx];
    float4 o;
    o.x = v.x*sc + sh; o.y = v.y*sc + sh; o.z = v.z*sc + sh; o.w = v.w*sc + sh;
    ((float4*)h)[idx] = o;
}

// ---------------- fp32 GEMM (used for proj): out[b][m][p] = A[m][:]·Bm[b][:][p] + bias[m] (+resid) ----------------
__global__ __launch_bounds__(256) void gemm_k(const float* __restrict__ A,
                                              const float* __restrict__ Bm,
                                              const float* __restrict__ bias,
                                              const float* __restrict__ resid,
                                              float* __restrict__ out,
                                              int Mdim) {
    __shared__ float Ast[16][68];
    __shared__ float Bs[16][68];
    int b  = blockIdx.z;
    int my = blockIdx.y;
    int nx = blockIdx.x;
    int t = threadIdx.x;
    int ty = t >> 4, tx = t & 15;
    const float* Ab = A + (size_t)my * 64 * 256;
    const float* Bb = Bm + (size_t)b * 256 * HW + nx * 64;
    float acc[4][4] = {};
    int lr  = t >> 2;
    int lc  = (t & 3) * 4;
    int brr = t >> 4;
    int bc4 = (t & 15) * 4;
    for (int k0 = 0; k0 < 256; k0 += 16) {
        float4 av = *(const float4*)(Ab + lr * 256 + k0 + lc);
        float4 bv = *(const float4*)(Bb + (size_t)(k0 + brr) * HW + bc4);
        Ast[lc + 0][lr] = av.x;
        Ast[lc + 1][lr] = av.y;
        Ast[lc + 2][lr] = av.z;
        Ast[lc + 3][lr] = av.w;
        *(float4*)&Bs[brr][bc4] = bv;
        __syncthreads();
        #pragma unroll
        for (int kk = 0; kk < 16; kk++) {
            float4 a4 = *(const float4*)&Ast[kk][ty * 4];
            float4 b4 = *(const float4*)&Bs[kk][tx * 4];
            acc[0][0] += a4.x*b4.x; acc[0][1] += a4.x*b4.y; acc[0][2] += a4.x*b4.z; acc[0][3] += a4.x*b4.w;
            acc[1][0] += a4.y*b4.x; acc[1][1] += a4.y*b4.y; acc[1][2] += a4.y*b4.z; acc[1][3] += a4.y*b4.w;
            acc[2][0] += a4.z*b4.x; acc[2][1] += a4.z*b4.y; acc[2][2] += a4.z*b4.z; acc[2][3] += a4.z*b4.w;
            acc[3][0] += a4.w*b4.x; acc[3][1] += a4.w*b4.y; acc[3][2] += a4.w*b4.z; acc[3][3] += a4.w*b4.w;
        }
        __syncthreads();
    }
    #pragma unroll
    for (int r = 0; r < 4; r++) {
        int m = my * 64 + ty * 4 + r;
        size_t off = ((size_t)b * Mdim + m) * HW + nx * 64 + tx * 4;
        float bsv = bias[m];
        float4 o;
        o.x = acc[r][0] + bsv; o.y = acc[r][1] + bsv; o.z = acc[r][2] + bsv; o.w = acc[r][3] + bsv;
        if (resid != nullptr) {
            float4 rv = *(const float4*)(resid + off);
            o.x += rv.x; o.y += rv.y; o.z += rv.z; o.w += rv.w;
        }
        *(float4*)(out + off) = o;
    }
}

// ---------------- QKV GEMM (fp32 math) with bf16 multi-layout epilogue ----------------
// my 0..3: Q head my  -> qt[(b,h)][p][d] bf16, scaled by QSCALE (transposed via LDS)
// my 4..7: K head my-4-> kt[(b,h)][p][d] bf16 (transposed via LDS)
// my 8..11:V head my-8-> vv[(b,h)][d][p] bf16 (direct)
__global__ __launch_bounds__(256) void gemm_qkv_k(const float* __restrict__ A,     // w_qkv [768][256]
                                                  const float* __restrict__ Bm,    // h [NB][256][HW]
                                                  const float* __restrict__ bias,  // [768]
                                                  unsigned short* __restrict__ qt,
                                                  unsigned short* __restrict__ kt,
                                                  unsigned short* __restrict__ vv) {
    __shared__ float Ast[16][68];
    __shared__ float Bs[16][68];
    __shared__ unsigned short T[64][72];   // [p][d] staging, 144B rows (16B aligned)
    int b  = blockIdx.z;
    int my = blockIdx.y;   // 0..11
    int nx = blockIdx.x;
    int t = threadIdx.x;
    int ty = t >> 4, tx = t & 15;
    const float* Ab = A + (size_t)my * 64 * 256;
    const float* Bb = Bm + (size_t)b * 256 * HW + nx * 64;
    float acc[4][4] = {};
    int lr  = t >> 2;
    int lc  = (t & 3) * 4;
    int brr = t >> 4;
    int bc4 = (t & 15) * 4;
    for (int k0 = 0; k0 < 256; k0 += 16) {
        float4 av = *(const float4*)(Ab + lr * 256 + k0 + lc);
        float4 bv = *(const float4*)(Bb + (size_t)(k0 + brr) * HW + bc4);
        Ast[lc + 0][lr] = av.x;
        Ast[lc + 1][lr] = av.y;
        Ast[lc + 2][lr] = av.z;
        Ast[lc + 3][lr] = av.w;
        *(float4*)&Bs[brr][bc4] = bv;
        __syncthreads();
        #pragma unroll
        for (int kk = 0; kk < 16; kk++) {
            float4 a4 = *(const float4*)&Ast[kk][ty * 4];
            float4 b4 = *(const float4*)&Bs[kk][tx * 4];
            acc[0][0] += a4.x*b4.x; acc[0][1] += a4.x*b4.y; acc[0][2] += a4.x*b4.z; acc[0][3] += a4.x*b4.w;
            acc[1][0] += a4.y*b4.x; acc[1][1] += a4.y*b4.y; acc[1][2] += a4.y*b4.z; acc[1][3] += a4.y*b4.w;
            acc[2][0] += a4.z*b4.x; acc[2][1] += a4.z*b4.y; acc[2][2] += a4.z*b4.z; acc[2][3] += a4.z*b4.w;
            acc[3][0] += a4.w*b4.x; acc[3][1] += a4.w*b4.y; acc[3][2] += a4.w*b4.z; acc[3][3] += a4.w*b4.w;
        }
        __syncthreads();
    }
    int sec = my >> 2;        // 0=q, 1=k, 2=v
    int hh  = my & 3;
    if (sec == 2) {
        // V: direct [d][p] bf16 store
        #pragma unroll
        for (int r = 0; r < 4; r++) {
            int d = ty * 4 + r;
            float bsv = bias[my * 64 + d];
            size_t off = ((size_t)(b * NH + hh) * 64 + d) * HW + nx * 64 + tx * 4;
            ushort4 o;
            o.x = f2bf(acc[r][0] + bsv); o.y = f2bf(acc[r][1] + bsv);
            o.z = f2bf(acc[r][2] + bsv); o.w = f2bf(acc[r][3] + bsv);
            *(ushort4*)(vv + off) = o;
        }
    } else {
        // Q/K: transpose through LDS -> [p][d] bf16
        float sc = (sec == 0) ? QSCALE : 1.f;
        #pragma unroll
        for (int r = 0; r < 4; r++) {
            float bsv = bias[my * 64 + ty * 4 + r];
            #pragma unroll
            for (int c = 0; c < 4; c++)
                T[tx * 4 + c][ty * 4 + r] = f2bf((acc[r][c] + bsv) * sc);
        }
        __syncthreads();
        unsigned short* dst = ((sec == 0) ? qt : kt) + ((size_t)(b * NH + hh) * HW + nx * 64) * 64;
        int p = t >> 2, cc = t & 3;
        *(uint4*)(dst + p * 64 + cc * 16)     = *(const uint4*)&T[p][cc * 16];
        *(uint4*)(dst + p * 64 + cc * 16 + 8) = *(const uint4*)&T[p][cc * 16 + 8];
    }
}

// ---------------- Flash attention, bf16 MFMA, i×j wave split ----------------
// qt,kt: [(b,h)][p][64] bf16 (Q pre-scaled by QSCALE); vv: [(b,h)][64][p] bf16.
// Block: 64-query tile, 4 waves = 2 i-halves (iw) x 2 j-halves (jw); per-wave 32i x 32j
// of every 64-j tile with its own online-softmax state; j-halves merged in epilogue.
// S^T = K·Q^T orientation (softmax per-lane-replicated, 2 shuffles per reduce).
//
// REGISTER BUDGET [r5/r6 post-mortem]: working set ≈ 110-130 VGPRs (oacc 32 +
// qf 16 + kreg/vreg 16 + pf 8 + sacc 16 + addr/ptrs). r5's (256,4) capped at 128
// -> spilled (WRITE 700MB); r6's no-bound let the heuristic pick 84 -> still
// spilled (WRITE 222MB). (256,2) sets the cap to 256: allocator takes what it
// needs, zero spills; occupancy falls out of actual usage (~4 waves/EU).
__global__ __launch_bounds__(256, 2) void attn_k(const unsigned short* __restrict__ qt,
                                                 const unsigned short* __restrict__ kt,
                                                 const unsigned short* __restrict__ vv,
                                                 float* __restrict__ attno) {
    __shared__ __align__(16) unsigned short smem[12288];  // 24KB: K | V | P
    unsigned short* Klds = smem;          // 64 rows(j) x 64(d), swizzled 16B chunks
    unsigned short* Vlds = smem + 4096;   // 64 rows(d) x 64(j), swizzled
    unsigned short* Pt   = smem + 8192;   // [wave][mi][chunk 0..63][8] fragment-ready, 8KB
    int t = threadIdx.x;
    int wave = t >> 6, lane = t & 63, quad = lane >> 4, l16 = lane & 15;
    int iw = wave & 1, jw = wave >> 1;
    int i0 = blockIdx.x * 64;
    int hh = blockIdx.y, b = blockIdx.z;
    const unsigned short* qb  = qt + (size_t)(b * NH + hh) * HW * 64;
    const unsigned short* kbp = kt + (size_t)(b * NH + hh) * HW * 64;
    const unsigned short* vbp = vv + (size_t)(b * NH + hh) * 64 * HW;

    // Q B-frags: lane holds Q[i = i0+iw*32+mi*16+l16][d = kc*32+quad*8 ..+8]
    bf16x8_t qf[2][2];
    #pragma unroll
    for (int mi = 0; mi < 2; mi++)
        #pragma unroll
        for (int kc = 0; kc < 2; kc++)
            qf[mi][kc] = *(const bf16x8_t*)(qb + (size_t)(i0 + iw * 32 + mi * 16 + l16) * 64 + kc * 32 + quad * 8);

    f32x4_t oacc[4][2];
    const f32x4_t zz = {0.f, 0.f, 0.f, 0.f};
    #pragma unroll
    for (int dt = 0; dt < 4; dt++) { oacc[dt][0] = zz; oacc[dt][1] = zz; }
    float m_pr[2] = {-INFINITY, -INFINITY};
    float l_sum[2] = {0.f, 0.f};

    // staging maps (constant per thread)
    int soffK[2], soffV[2], slds[2];
    #pragma unroll
    for (int n = 0; n < 2; n++) {
        int s = n * 256 + t;
        int row = s >> 3;
        int c = (s & 7) ^ (row & 7);
        soffK[n] = row * 128 + c * 16;          // bytes (row=j, 128B rows)
        soffV[n] = row * (HW * 2) + c * 16;     // bytes (row=d, stride HW*2)
        slds[n] = s * 8;                        // ushort index
    }
    uint4 kreg[2], vreg[2];
    {
        const char* kbase = (const char*)kbp;
        const char* vbase = (const char*)vbp;
        kreg[0] = *(const uint4*)(kbase + soffK[0]); kreg[1] = *(const uint4*)(kbase + soffK[1]);
        vreg[0] = *(const uint4*)(vbase + soffV[0]); vreg[1] = *(const uint4*)(vbase + soffV[1]);
    }

    for (int jt = 0; jt < 64; jt++) {
        __syncthreads();   // previous tile fully consumed
        *(uint4*)&Klds[slds[0]] = kreg[0]; *(uint4*)&Klds[slds[1]] = kreg[1];
        *(uint4*)&Vlds[slds[0]] = vreg[0]; *(uint4*)&Vlds[slds[1]] = vreg[1];
        __syncthreads();   // tiles ready
        if (jt < 63) {     // prefetch next tile into regs
            const char* kbase = (const char*)kbp + (size_t)(jt + 1) * 8192;
            const char* vbase = (const char*)vbp + (size_t)(jt + 1) * 128;
            kreg[0] = *(const uint4*)(kbase + soffK[0]); kreg[1] = *(const uint4*)(kbase + soffK[1]);
            vreg[0] = *(const uint4*)(vbase + soffV[0]); vreg[1] = *(const uint4*)(vbase + soffV[1]);
        }

        // ---- S^T = K·Q^T on this wave's 32 j x 32 i ----
        f32x4_t sacc[2][2];
        sacc[0][0] = zz; sacc[0][1] = zz; sacc[1][0] = zz; sacc[1][1] = zz;
        #pragma unroll
        for (int nj = 0; nj < 2; nj++) {
            int j = jw * 32 + nj * 16 + l16;        // A-operand row
            int rb = j * 8;
            bf16x8_t kf0 = *(const bf16x8_t*)&Klds[(rb + ((quad    ) ^ (j & 7))) * 8];
            bf16x8_t kf1 = *(const bf16x8_t*)&Klds[(rb + ((4 + quad) ^ (j & 7))) * 8];
            #pragma unroll
            for (int mi = 0; mi < 2; mi++) {
                sacc[mi][nj] = __builtin_amdgcn_mfma_f32_16x16x32_bf16(kf0, qf[mi][0], sacc[mi][nj], 0, 0, 0);
                sacc[mi][nj] = __builtin_amdgcn_mfma_f32_16x16x32_bf16(kf1, qf[mi][1], sacc[mi][nj], 0, 0, 0);
            }
        }

        // ---- online softmax (base-2) per i-tile; state per-lane-replicated, j-half-local ----
        float alpha_[2];
        #pragma unroll
        for (int mi = 0; mi < 2; mi++) {
            float m = sacc[mi][0][0];
            #pragma unroll
            for (int nj = 0; nj < 2; nj++)
                #pragma unroll
                for (int r = 0; r < 4; r++) m = fmaxf(m, sacc[mi][nj][r]);
            m = fmaxf(m, __shfl_xor(m, 16));
            m = fmaxf(m, __shfl_xor(m, 32));
            float mnew = fmaxf(m_pr[mi], m);
            float a = __builtin_amdgcn_exp2f(m_pr[mi] - mnew);
            alpha_[mi] = a;
            float rs = 0.f;
            #pragma unroll
            for (int nj = 0; nj < 2; nj++)
                #pragma unroll
                for (int r = 0; r < 4; r++) {
                    float p = __builtin_amdgcn_exp2f(sacc[mi][nj][r] - mnew);
                    sacc[mi][nj][r] = p;
                    rs += p;
                }
            rs += __shfl_xor(rs, 16);
            rs += __shfl_xor(rs, 32);
            l_sum[mi] = l_sum[mi] * a + rs;
            m_pr[mi] = mnew;

            // P -> wave-private LDS, fragment-ready: writer (quad,l16) holds
            // P[j' = nj*16+quad*4+r][i' = mi*16+l16]; reader chunk = rq*16+l16 with
            // j' = rq*8+idx  =>  rq = nj*2+(quad>>1), halfword off 4*(quad&1).
            #pragma unroll
            for (int nj = 0; nj < 2; nj++) {
                unsigned lo = (unsigned)f2bf(sacc[mi][nj][0]) | ((unsigned)f2bf(sacc[mi][nj][1]) << 16);
                unsigned hi = (unsigned)f2bf(sacc[mi][nj][2]) | ((unsigned)f2bf(sacc[mi][nj][3]) << 16);
                int chunk = (nj * 2 + (quad >> 1)) * 16 + l16;
                *(uint2*)&Pt[((wave * 2 + mi) * 64 + chunk) * 8 + 4 * (quad & 1)] = make_uint2(lo, hi);
            }
        }

        // rescale O by alpha (registers only)
        #pragma unroll
        for (int dt = 0; dt < 4; dt++) { oacc[dt][0] *= alpha_[0]; oacc[dt][1] *= alpha_[1]; }

        // Wave-private P round-trip. COMPILER barrier only: stops the TBAA hoist of
        // the bf16x8 P ds_reads above the P ds_writes (r2 failure). No HW wait
        // needed: same-wave DS ops are processed in order by the LDS pipeline.
        // (__threadfence_block here cost s_waitcnt vmcnt(0) -> drained the K/V
        // global prefetch every iteration. [r6 post-mortem])
        asm volatile("" ::: "memory");

        // ---- PV: O^T[d][i] += V[d][j-half]·P[j-half][i], K-dim = this wave's 32 j ----
        bf16x8_t pf[2];
        pf[0] = *(const bf16x8_t*)&Pt[((wave * 2 + 0) * 64 + quad * 16 + l16) * 8];
        pf[1] = *(const bf16x8_t*)&Pt[((wave * 2 + 1) * 64 + quad * 16 + l16) * 8];
        #pragma unroll
        for (int dt = 0; dt < 4; dt++) {
            int d = dt * 16 + l16;
            bf16x8_t vf = *(const bf16x8_t*)&Vlds[(d * 8 + ((jw * 4 + quad) ^ (d & 7))) * 8];
            oacc[dt][0] = __builtin_amdgcn_mfma_f32_16x16x32_bf16(vf, pf[0], oacc[dt][0], 0, 0, 0);
            oacc[dt][1] = __builtin_amdgcn_mfma_f32_16x16x32_bf16(vf, pf[1], oacc[dt][1], 0, 0, 0);
        }
    }

    // ---- epilogue: merge the two j-halves (split-k flash rescale), write O^T fp32 ----
    __syncthreads();                       // all K/V/P consumption done; reuse smem
    float* Obuf = (float*)smem;            // [iw][64 d][32 i'] = 16KB
    float2* ml  = (float2*)Pt;             // [iw][32 i'] (m, l)
    if (jw == 0) {
        #pragma unroll
        for (int dt = 0; dt < 4; dt++)
            #pragma unroll
            for (int mi = 0; mi < 2; mi++)
                #pragma unroll
                for (int r = 0; r < 4; r++)
                    Obuf[iw * 2048 + (dt * 16 + quad * 4 + r) * 32 + mi * 16 + l16] = oacc[dt][mi][r];
        if (quad == 0) {
            ml[iw * 32 + l16]      = make_float2(m_pr[0], l_sum[0]);
            ml[iw * 32 + 16 + l16] = make_float2(m_pr[1], l_sum[1]);
        }
    }
    __syncthreads();
    if (jw == 1) {
        float c0[2], c1[2];
        #pragma unroll
        for (int mi = 0; mi < 2; mi++) {
            float2 s0 = ml[iw * 32 + mi * 16 + l16];
            float mm = fmaxf(s0.x, m_pr[mi]);
            float a0 = __builtin_amdgcn_exp2f(s0.x - mm);
            float a1 = __builtin_amdgcn_exp2f(m_pr[mi] - mm);
            float l  = s0.y * a0 + l_sum[mi] * a1;
            c0[mi] = a0 / l; c1[mi] = a1 / l;
        }
        float* ob = attno + (size_t)(b * NH + hh) * 64 * HW + i0 + iw * 32;
        #pragma unroll
        for (int dt = 0; dt < 4; dt++)
            #pragma unroll
            for (int mi = 0; mi < 2; mi++)
                #pragma unroll
                for (int r = 0; r < 4; r++) {
                    int d = dt * 16 + quad * 4 + r;
                    float v = Obuf[iw * 2048 + d * 32 + mi * 16 + l16] * c0[mi] + oacc[dt][mi][r] * c1[mi];
                    ob[(size_t)d * HW + mi * 16 + l16] = v;
                }
    }
}

extern "C" void kernel_launch(void* const* d_in, const int* in_sizes, int n_in,
                              void* d_out, int out_size, void* d_ws, size_t ws_size,
                              hipStream_t stream) {
    const float* x      = (const float*)d_in[0];
    const float* gamma  = (const float*)d_in[1];
    const float* beta   = (const float*)d_in[2];
    const float* w_qkv  = (const float*)d_in[3];
    const float* b_qkv  = (const float*)d_in[4];
    const float* w_proj = (const float*)d_in[5];
    const float* b_proj = (const float*)d_in[6];
    float* out = (float*)d_out;

    // ws: stats[256] | attno fp32 [4M] | qt bf16 [4M] | kt bf16 [4M] | vv bf16 [4M]  => ~41 MB
    float* stats = (float*)d_ws;
    float* attno = stats + 256;
    unsigned short* qt = (unsigned short*)(attno + (size_t)NB * C_ * HW);
    unsigned short* kt = qt + (size_t)NB * NH * HW * 64;
    unsigned short* vv = kt + (size_t)NB * NH * HW * 64;
    float* h = out;  // reuse d_out as GroupNorm output; consumed by gemm_qkv, overwritten by final GEMM

    gn_stats_k<<<32, 256, 0, stream>>>(x, stats);
    gn_apply_k<<<NB * C_ * HW / 4 / 256, 256, 0, stream>>>(x, gamma, beta, stats, h);
    gemm_qkv_k<<<dim3(HW / 64, 12, NB), 256, 0, stream>>>(w_qkv, h, b_qkv, qt, kt, vv);
    attn_k<<<dim3(HW / 64, NH, NB), 256, 0, stream>>>(qt, kt, vv, attno);
    gemm_k<<<dim3(HW / 64, 4, NB), 256, 0, stream>>>(w_proj, attno, b_proj, x, out, 256);
}

// Round 8
// 367.498 us; speedup vs baseline: 1.4323x; 1.4030x over previous
//
#include <hip/hip_runtime.h>
#include <math.h>

#define NB 4
#define C_ 256
#define NG 8
#define CPG 32
#define HW 4096
#define NH 4
#define HD 64
#define EPS 1e-5f
#define QSCALE 0.1803368801111204f  /* 0.125 * log2(e): folds 1/sqrt(64) and base-2 softmax */

typedef __attribute__((ext_vector_type(8))) short bf16x8_t;
typedef __attribute__((ext_vector_type(4))) float f32x4_t;
typedef const __attribute__((address_space(1))) void g_void;
typedef __attribute__((address_space(3))) void l_void;

__device__ __forceinline__ unsigned short f2bf(float f) {
    unsigned u = __float_as_uint(f);
    u += 0x7FFFu + ((u >> 16) & 1u);   // RNE
    return (unsigned short)(u >> 16);
}

// ---------------- GroupNorm stats: one block per (b,g); group data is contiguous ----------------
__global__ __launch_bounds__(256) void gn_stats_k(const float* __restrict__ x,
                                                  float* __restrict__ stats) {
    int bg = blockIdx.x;  // 0..31
    const float4* base = (const float4*)(x + (size_t)bg * CPG * HW);
    const int n4 = CPG * HW / 4;  // 32768
    float s = 0.f, ss = 0.f;
    for (int i = threadIdx.x; i < n4; i += 256) {
        float4 v = base[i];
        s  += v.x + v.y + v.z + v.w;
        ss += v.x*v.x + v.y*v.y + v.z*v.z + v.w*v.w;
    }
    #pragma unroll
    for (int off = 32; off > 0; off >>= 1) {
        s  += __shfl_down(s, off);
        ss += __shfl_down(ss, off);
    }
    __shared__ float rs[4], rss[4];
    int wv = threadIdx.x >> 6;
    if ((threadIdx.x & 63) == 0) { rs[wv] = s; rss[wv] = ss; }
    __syncthreads();
    if (threadIdx.x == 0) {
        float S  = rs[0] + rs[1] + rs[2] + rs[3];
        float SS = rss[0] + rss[1] + rss[2] + rss[3];
        const float inv = 1.f / (float)(CPG * HW);
        float mean = S * inv;
        float var  = SS * inv - mean * mean;
        stats[2*bg]   = mean;
        stats[2*bg+1] = rsqrtf(var + EPS);
    }
}

// ---------------- GroupNorm apply (elementwise, float4) ----------------
__global__ __launch_bounds__(256) void gn_apply_k(const float* __restrict__ x,
                                                  const float* __restrict__ gamma,
                                                  const float* __restrict__ beta,
                                                  const float* __restrict__ stats,
                                                  float* __restrict__ h) {
    int idx = blockIdx.x * 256 + threadIdx.x;     // float4 index
    int bc = idx / (HW / 4);                       // b*256+c
    int b = bc >> 8, c = bc & 255;
    int bg = b * NG + (c >> 5);
    float mean = stats[2*bg], rstd = stats[2*bg+1];
    float sc = gamma[c] * rstd;
    float sh = beta[c] - mean * sc;
    float4 v = ((const float4*)x)[idx];
    float4 o;
    o.x = v.x*sc + sh; o.y = v.y*sc + sh; o.z = v.z*sc + sh; o.w = v.w*sc + sh;
    ((float4*)h)[idx] = o;
}

// ---------------- fp32 GEMM (used for proj): out[b][m][p] = A[m][:]·Bm[b][:][p] + bias[m] (+resid) ----------------
__global__ __launch_bounds__(256) void gemm_k(const float* __restrict__ A,
                                              const float* __restrict__ Bm,
                                              const float* __restrict__ bias,
                                              const float* __restrict__ resid,
                                              float* __restrict__ out,
                                              int Mdim) {
    __shared__ float Ast[16][68];
    __shared__ float Bs[16][68];
    int b  = blockIdx.z;
    int my = blockIdx.y;
    int nx = blockIdx.x;
    int t = threadIdx.x;
    int ty = t >> 4, tx = t & 15;
    const float* Ab = A + (size_t)my * 64 * 256;
    const float* Bb = Bm + (size_t)b * 256 * HW + nx * 64;
    float acc[4][4] = {};
    int lr  = t >> 2;
    int lc  = (t & 3) * 4;
    int brr = t >> 4;
    int bc4 = (t & 15) * 4;
    for (int k0 = 0; k0 < 256; k0 += 16) {
        float4 av = *(const float4*)(Ab + lr * 256 + k0 + lc);
        float4 bv = *(const float4*)(Bb + (size_t)(k0 + brr) * HW + bc4);
        Ast[lc + 0][lr] = av.x;
        Ast[lc + 1][lr] = av.y;
        Ast[lc + 2][lr] = av.z;
        Ast[lc + 3][lr] = av.w;
        *(float4*)&Bs[brr][bc4] = bv;
        __syncthreads();
        #pragma unroll
        for (int kk = 0; kk < 16; kk++) {
            float4 a4 = *(const float4*)&Ast[kk][ty * 4];
            float4 b4 = *(const float4*)&Bs[kk][tx * 4];
            acc[0][0] += a4.x*b4.x; acc[0][1] += a4.x*b4.y; acc[0][2] += a4.x*b4.z; acc[0][3] += a4.x*b4.w;
            acc[1][0] += a4.y*b4.x; acc[1][1] += a4.y*b4.y; acc[1][2] += a4.y*b4.z; acc[1][3] += a4.y*b4.w;
            acc[2][0] += a4.z*b4.x; acc[2][1] += a4.z*b4.y; acc[2][2] += a4.z*b4.z; acc[2][3] += a4.z*b4.w;
            acc[3][0] += a4.w*b4.x; acc[3][1] += a4.w*b4.y; acc[3][2] += a4.w*b4.z; acc[3][3] += a4.w*b4.w;
        }
        __syncthreads();
    }
    #pragma unroll
    for (int r = 0; r < 4; r++) {
        int m = my * 64 + ty * 4 + r;
        size_t off = ((size_t)b * Mdim + m) * HW + nx * 64 + tx * 4;
        float bsv = bias[m];
        float4 o;
        o.x = acc[r][0] + bsv; o.y = acc[r][1] + bsv; o.z = acc[r][2] + bsv; o.w = acc[r][3] + bsv;
        if (resid != nullptr) {
            float4 rv = *(const float4*)(resid + off);
            o.x += rv.x; o.y += rv.y; o.z += rv.z; o.w += rv.w;
        }
        *(float4*)(out + off) = o;
    }
}

// ---------------- QKV GEMM (fp32 math) with bf16 multi-layout epilogue ----------------
// my 0..3: Q head my  -> qt[(b,h)][p][d] bf16, scaled by QSCALE (transposed via LDS)
// my 4..7: K head my-4-> kt[(b,h)][p][d] bf16 (transposed via LDS)
// my 8..11:V head my-8-> vv[(b,h)][d][p] bf16 (direct)
__global__ __launch_bounds__(256) void gemm_qkv_k(const float* __restrict__ A,     // w_qkv [768][256]
                                                  const float* __restrict__ Bm,    // h [NB][256][HW]
                                                  const float* __restrict__ bias,  // [768]
                                                  unsigned short* __restrict__ qt,
                                                  unsigned short* __restrict__ kt,
                                                  unsigned short* __restrict__ vv) {
    __shared__ float Ast[16][68];
    __shared__ float Bs[16][68];
    __shared__ unsigned short T[64][72];   // [p][d] staging, 144B rows (16B aligned)
    int b  = blockIdx.z;
    int my = blockIdx.y;   // 0..11
    int nx = blockIdx.x;
    int t = threadIdx.x;
    int ty = t >> 4, tx = t & 15;
    const float* Ab = A + (size_t)my * 64 * 256;
    const float* Bb = Bm + (size_t)b * 256 * HW + nx * 64;
    float acc[4][4] = {};
    int lr  = t >> 2;
    int lc  = (t & 3) * 4;
    int brr = t >> 4;
    int bc4 = (t & 15) * 4;
    for (int k0 = 0; k0 < 256; k0 += 16) {
        float4 av = *(const float4*)(Ab + lr * 256 + k0 + lc);
        float4 bv = *(const float4*)(Bb + (size_t)(k0 + brr) * HW + bc4);
        Ast[lc + 0][lr] = av.x;
        Ast[lc + 1][lr] = av.y;
        Ast[lc + 2][lr] = av.z;
        Ast[lc + 3][lr] = av.w;
        *(float4*)&Bs[brr][bc4] = bv;
        __syncthreads();
        #pragma unroll
        for (int kk = 0; kk < 16; kk++) {
            float4 a4 = *(const float4*)&Ast[kk][ty * 4];
            float4 b4 = *(const float4*)&Bs[kk][tx * 4];
            acc[0][0] += a4.x*b4.x; acc[0][1] += a4.x*b4.y; acc[0][2] += a4.x*b4.z; acc[0][3] += a4.x*b4.w;
            acc[1][0] += a4.y*b4.x; acc[1][1] += a4.y*b4.y; acc[1][2] += a4.y*b4.z; acc[1][3] += a4.y*b4.w;
            acc[2][0] += a4.z*b4.x; acc[2][1] += a4.z*b4.y; acc[2][2] += a4.z*b4.z; acc[2][3] += a4.z*b4.w;
            acc[3][0] += a4.w*b4.x; acc[3][1] += a4.w*b4.y; acc[3][2] += a4.w*b4.z; acc[3][3] += a4.w*b4.w;
        }
        __syncthreads();
    }
    int sec = my >> 2;        // 0=q, 1=k, 2=v
    int hh  = my & 3;
    if (sec == 2) {
        // V: direct [d][p] bf16 store
        #pragma unroll
        for (int r = 0; r < 4; r++) {
            int d = ty * 4 + r;
            float bsv = bias[my * 64 + d];
            size_t off = ((size_t)(b * NH + hh) * 64 + d) * HW + nx * 64 + tx * 4;
            ushort4 o;
            o.x = f2bf(acc[r][0] + bsv); o.y = f2bf(acc[r][1] + bsv);
            o.z = f2bf(acc[r][2] + bsv); o.w = f2bf(acc[r][3] + bsv);
            *(ushort4*)(vv + off) = o;
        }
    } else {
        // Q/K: transpose through LDS -> [p][d] bf16
        float sc = (sec == 0) ? QSCALE : 1.f;
        #pragma unroll
        for (int r = 0; r < 4; r++) {
            float bsv = bias[my * 64 + ty * 4 + r];
            #pragma unroll
            for (int c = 0; c < 4; c++)
                T[tx * 4 + c][ty * 4 + r] = f2bf((acc[r][c] + bsv) * sc);
        }
        __syncthreads();
        unsigned short* dst = ((sec == 0) ? qt : kt) + ((size_t)(b * NH + hh) * HW + nx * 64) * 64;
        int p = t >> 2, cc = t & 3;
        *(uint4*)(dst + p * 64 + cc * 16)     = *(const uint4*)&T[p][cc * 16];
        *(uint4*)(dst + p * 64 + cc * 16 + 8) = *(const uint4*)&T[p][cc * 16 + 8];
    }
}

// ---------------- Flash attention, bf16 MFMA, i×j wave split, async-staged ----------------
// qt,kt: [(b,h)][p][64] bf16 (Q pre-scaled by QSCALE); vv: [(b,h)][64][p] bf16.
// Block: 64-query tile, 4 waves = 2 i-halves (iw) x 2 j-halves (jw); per-wave 32i x 32j
// with its own online-softmax state; j-halves merged in epilogue (split-k rescale).
//
// K/V staging: __builtin_amdgcn_global_load_lds width=16 into DOUBLE-buffered LDS —
// no VGPR round-trip (removes the 16-reg prefetch that drove r5-r7 spills:
// WRITE_SIZE 660MB scratch @ VGPR=60). Swizzle preserved by permuting which
// global chunk each lane fetches (dest is wave-uniform base + lane*16, m104).
// Pipeline per iter: s_waitcnt vmcnt(0); raw s_barrier; issue next tile's loads;
// compute current. One barrier/iter, loads in flight across full compute phase
// (raw asm barrier avoids __syncthreads' post-issue full drain).
// amdgpu_waves_per_eu(2,4): max=4 blocks the backend's max-occupancy VGPR squeeze
// (two-arg launch_bounds pinned arch VGPRs to 60 and spilled — r5/r7); budget
// 512/4=128 >= ~90-reg working set. LDS 40KB caps at 4 blocks/CU anyway.
__global__ __launch_bounds__(256) __attribute__((amdgpu_waves_per_eu(2, 4)))
void attn_k(const unsigned short* __restrict__ qt,
            const unsigned short* __restrict__ kt,
            const unsigned short* __restrict__ vv,
            float* __restrict__ attno) {
    // ushort idx: K0 0..4095 | K1 4096..8191 | V0 8192..12287 | V1 12288..16383 | Pt 16384..20479
    __shared__ __align__(16) unsigned short smem[20480];  // 40KB
    unsigned short* Pt = smem + 16384;
    int t = threadIdx.x;
    int wave = t >> 6, lane = t & 63, quad = lane >> 4, l16 = lane & 15;
    int iw = wave & 1, jw = wave >> 1;
    int i0 = blockIdx.x * 64;
    int hh = blockIdx.y, b = blockIdx.z;
    const unsigned short* qb = qt + (size_t)(b * NH + hh) * HW * 64;
    const char* kbp = (const char*)(kt + (size_t)(b * NH + hh) * HW * 64);
    const char* vbp = (const char*)(vv + (size_t)(b * NH + hh) * 64 * HW);

    // Q B-frags: lane holds Q[i = i0+iw*32+mi*16+l16][d = kc*32+quad*8 ..+8]
    bf16x8_t qf[2][2];
    #pragma unroll
    for (int mi = 0; mi < 2; mi++)
        #pragma unroll
        for (int kc = 0; kc < 2; kc++)
            qf[mi][kc] = *(const bf16x8_t*)(qb + (size_t)(i0 + iw * 32 + mi * 16 + l16) * 64 + kc * 32 + quad * 8);

    f32x4_t oacc[4][2];
    const f32x4_t zz = {0.f, 0.f, 0.f, 0.f};
    #pragma unroll
    for (int dt = 0; dt < 4; dt++) { oacc[dt][0] = zz; oacc[dt][1] = zz; }
    float m_pr[2] = {-INFINITY, -INFINITY};
    float l_sum[2] = {0.f, 0.f};

    // staging maps: thread t handles tile slot s = n*256+t; lane's data lands at
    // LDS slot s (wave-uniform base n*2048+wave*512 ushorts + lane*16B); the lane
    // FETCHES the swizzled global chunk so reads keep the XOR layout.
    int soffK[2], soffV[2], ldsoff[2];
    #pragma unroll
    for (int n = 0; n < 2; n++) {
        int s = n * 256 + t;
        int row = s >> 3;
        int c = (s & 7) ^ (row & 7);
        soffK[n] = row * 128 + c * 16;          // bytes (row=j, 128B rows)
        soffV[n] = row * (HW * 2) + c * 16;     // bytes (row=d, stride HW*2)
        ldsoff[n] = n * 2048 + wave * 512;      // ushort idx, wave-uniform
    }

    // preload tile 0 -> K0/V0
    #pragma unroll
    for (int n = 0; n < 2; n++) {
        __builtin_amdgcn_global_load_lds((g_void*)(kbp + soffK[n]), (l_void*)(smem + ldsoff[n]), 16, 0, 0);
        __builtin_amdgcn_global_load_lds((g_void*)(vbp + soffV[n]), (l_void*)(smem + 8192 + ldsoff[n]), 16, 0, 0);
    }

    for (int jt = 0; jt < 64; jt++) {
        // tile jt's deposits (this wave's) complete; barrier makes all waves' complete
        // AND proves everyone finished computing tile jt-1 (so buf[(jt+1)&1] is free).
        asm volatile("s_waitcnt vmcnt(0)" ::: "memory");
        asm volatile("s_barrier" ::: "memory");
        if (jt < 63) {
            const char* kb = kbp + (size_t)(jt + 1) * 8192;
            const char* vb = vbp + (size_t)(jt + 1) * 128;
            int bb = ((jt + 1) & 1) * 4096;
            #pragma unroll
            for (int n = 0; n < 2; n++) {
                __builtin_amdgcn_global_load_lds((g_void*)(kb + soffK[n]), (l_void*)(smem + bb + ldsoff[n]), 16, 0, 0);
                __builtin_amdgcn_global_load_lds((g_void*)(vb + soffV[n]), (l_void*)(smem + 8192 + bb + ldsoff[n]), 16, 0, 0);
            }
        }
        const unsigned short* Kc = smem + (jt & 1) * 4096;
        const unsigned short* Vc = smem + 8192 + (jt & 1) * 4096;

        // ---- S^T = K·Q^T on this wave's 32 j x 32 i ----
        f32x4_t sacc[2][2];
        sacc[0][0] = zz; sacc[0][1] = zz; sacc[1][0] = zz; sacc[1][1] = zz;
        #pragma unroll
        for (int nj = 0; nj < 2; nj++) {
            int j = jw * 32 + nj * 16 + l16;        // A-operand row
            int rb = j * 8;
            bf16x8_t kf0 = *(const bf16x8_t*)&Kc[(rb + ((quad    ) ^ (j & 7))) * 8];
            bf16x8_t kf1 = *(const bf16x8_t*)&Kc[(rb + ((4 + quad) ^ (j & 7))) * 8];
            #pragma unroll
            for (int mi = 0; mi < 2; mi++) {
                sacc[mi][nj] = __builtin_amdgcn_mfma_f32_16x16x32_bf16(kf0, qf[mi][0], sacc[mi][nj], 0, 0, 0);
                sacc[mi][nj] = __builtin_amdgcn_mfma_f32_16x16x32_bf16(kf1, qf[mi][1], sacc[mi][nj], 0, 0, 0);
            }
        }

        // ---- online softmax (base-2) per i-tile; state per-lane-replicated, j-half-local ----
        float alpha_[2];
        #pragma unroll
        for (int mi = 0; mi < 2; mi++) {
            float m = sacc[mi][0][0];
            #pragma unroll
            for (int nj = 0; nj < 2; nj++)
                #pragma unroll
                for (int r = 0; r < 4; r++) m = fmaxf(m, sacc[mi][nj][r]);
            m = fmaxf(m, __shfl_xor(m, 16));
            m = fmaxf(m, __shfl_xor(m, 32));
            float mnew = fmaxf(m_pr[mi], m);
            float a = __builtin_amdgcn_exp2f(m_pr[mi] - mnew);
            alpha_[mi] = a;
            float rs = 0.f;
            #pragma unroll
            for (int nj = 0; nj < 2; nj++)
                #pragma unroll
                for (int r = 0; r < 4; r++) {
                    float p = __builtin_amdgcn_exp2f(sacc[mi][nj][r] - mnew);
                    sacc[mi][nj][r] = p;
                    rs += p;
                }
            rs += __shfl_xor(rs, 16);
            rs += __shfl_xor(rs, 32);
            l_sum[mi] = l_sum[mi] * a + rs;
            m_pr[mi] = mnew;

            // P -> wave-private LDS, fragment-ready: writer (quad,l16) holds
            // P[j' = nj*16+quad*4+r][i' = mi*16+l16]; reader chunk = rq*16+l16 with
            // j' = rq*8+idx  =>  rq = nj*2+(quad>>1), halfword off 4*(quad&1).
            #pragma unroll
            for (int nj = 0; nj < 2; nj++) {
                unsigned lo = (unsigned)f2bf(sacc[mi][nj][0]) | ((unsigned)f2bf(sacc[mi][nj][1]) << 16);
                unsigned hi = (unsigned)f2bf(sacc[mi][nj][2]) | ((unsigned)f2bf(sacc[mi][nj][3]) << 16);
                int chunk = (nj * 2 + (quad >> 1)) * 16 + l16;
                *(uint2*)&Pt[((wave * 2 + mi) * 64 + chunk) * 8 + 4 * (quad & 1)] = make_uint2(lo, hi);
            }
        }

        // rescale O by alpha (registers only)
        #pragma unroll
        for (int dt = 0; dt < 4; dt++) { oacc[dt][0] *= alpha_[0]; oacc[dt][1] *= alpha_[1]; }

        // Wave-private P round-trip: COMPILER barrier only (stops the r2 TBAA hoist);
        // same-wave DS ops execute in order, no HW wait needed (validated r7).
        asm volatile("" ::: "memory");

        // ---- PV: O^T[d][i] += V[d][j-half]·P[j-half][i], K-dim = this wave's 32 j ----
        bf16x8_t pf[2];
        pf[0] = *(const bf16x8_t*)&Pt[((wave * 2 + 0) * 64 + quad * 16 + l16) * 8];
        pf[1] = *(const bf16x8_t*)&Pt[((wave * 2 + 1) * 64 + quad * 16 + l16) * 8];
        #pragma unroll
        for (int dt = 0; dt < 4; dt++) {
            int d = dt * 16 + l16;
            bf16x8_t vf = *(const bf16x8_t*)&Vc[(d * 8 + ((jw * 4 + quad) ^ (d & 7))) * 8];
            oacc[dt][0] = __builtin_amdgcn_mfma_f32_16x16x32_bf16(vf, pf[0], oacc[dt][0], 0, 0, 0);
            oacc[dt][1] = __builtin_amdgcn_mfma_f32_16x16x32_bf16(vf, pf[1], oacc[dt][1], 0, 0, 0);
        }
    }

    // ---- epilogue: merge the two j-halves (split-k flash rescale), write O^T fp32 ----
    __syncthreads();                       // all K/V/P consumption done; reuse smem
    float* Obuf = (float*)smem;            // [iw][64 d][32 i'] = 16KB (K0+K1 region)
    float2* ml  = (float2*)Pt;             // [iw][32 i'] (m, l)
    if (jw == 0) {
        #pragma unroll
        for (int dt = 0; dt < 4; dt++)
            #pragma unroll
            for (int mi = 0; mi < 2; mi++)
                #pragma unroll
                for (int r = 0; r < 4; r++)
                    Obuf[iw * 2048 + (dt * 16 + quad * 4 + r) * 32 + mi * 16 + l16] = oacc[dt][mi][r];
        if (quad == 0) {
            ml[iw * 32 + l16]      = make_float2(m_pr[0], l_sum[0]);
            ml[iw * 32 + 16 + l16] = make_float2(m_pr[1], l_sum[1]);
        }
    }
    __syncthreads();
    if (jw == 1) {
        float c0[2], c1[2];
        #pragma unroll
        for (int mi = 0; mi < 2; mi++) {
            float2 s0 = ml[iw * 32 + mi * 16 + l16];
            float mm = fmaxf(s0.x, m_pr[mi]);
            float a0 = __builtin_amdgcn_exp2f(s0.x - mm);
            float a1 = __builtin_amdgcn_exp2f(m_pr[mi] - mm);
            float l  = s0.y * a0 + l_sum[mi] * a1;
            c0[mi] = a0 / l; c1[mi] = a1 / l;
        }
        float* ob = attno + (size_t)(b * NH + hh) * 64 * HW + i0 + iw * 32;
        #pragma unroll
        for (int dt = 0; dt < 4; dt++)
            #pragma unroll
            for (int mi = 0; mi < 2; mi++)
                #pragma unroll
                for (int r = 0; r < 4; r++) {
                    int d = dt * 16 + quad * 4 + r;
                    float v = Obuf[iw * 2048 + d * 32 + mi * 16 + l16] * c0[mi] + oacc[dt][mi][r] * c1[mi];
                    ob[(size_t)d * HW + mi * 16 + l16] = v;
                }
    }
}

extern "C" void kernel_launch(void* const* d_in, const int* in_sizes, int n_in,
                              void* d_out, int out_size, void* d_ws, size_t ws_size,
                              hipStream_t stream) {
    const float* x      = (const float*)d_in[0];
    const float* gamma  = (const float*)d_in[1];
    const float* beta   = (const float*)d_in[2];
    const float* w_qkv  = (const float*)d_in[3];
    const float* b_qkv  = (const float*)d_in[4];
    const float* w_proj = (const float*)d_in[5];
    const float* b_proj = (const float*)d_in[6];
    float* out = (float*)d_out;

    // ws: stats[256] | attno fp32 [4M] | qt bf16 [4M] | kt bf16 [4M] | vv bf16 [4M]  => ~41 MB
    float* stats = (float*)d_ws;
    float* attno = stats + 256;
    unsigned short* qt = (unsigned short*)(attno + (size_t)NB * C_ * HW);
    unsigned short* kt = qt + (size_t)NB * NH * HW * 64;
    unsigned short* vv = kt + (size_t)NB * NH * HW * 64;
    float* h = out;  // reuse d_out as GroupNorm output; consumed by gemm_qkv, overwritten by final GEMM

    gn_stats_k<<<32, 256, 0, stream>>>(x, stats);
    gn_apply_k<<<NB * C_ * HW / 4 / 256, 256, 0, stream>>>(x, gamma, beta, stats, h);
    gemm_qkv_k<<<dim3(HW / 64, 12, NB), 256, 0, stream>>>(w_qkv, h, b_qkv, qt, kt, vv);
    attn_k<<<dim3(HW / 64, NH, NB), 256, 0, stream>>>(qt, kt, vv, attno);
    gemm_k<<<dim3(HW / 64, 4, NB), 256, 0, stream>>>(w_proj, attno, b_proj, x, out, 256);
}

// Round 9
// 289.720 us; speedup vs baseline: 1.8168x; 1.2685x over previous
//
#include <hip/hip_runtime.h>
#include <math.h>

#define NB 4
#define C_ 256
#define NG 8
#define CPG 32
#define HW 4096
#define NH 4
#define HD 64
#define EPS 1e-5f
#define QSCALE 0.1803368801111204f  /* 0.125 * log2(e): folds 1/sqrt(64) and base-2 softmax */

typedef __attribute__((ext_vector_type(8))) short bf16x8_t;
typedef __attribute__((ext_vector_type(4))) float f32x4_t;
typedef const __attribute__((address_space(1))) void g_void;
typedef __attribute__((address_space(3))) void l_void;

__device__ __forceinline__ unsigned short f2bf(float f) {
    unsigned u = __float_as_uint(f);
    u += 0x7FFFu + ((u >> 16) & 1u);   // RNE
    return (unsigned short)(u >> 16);
}

// ---------------- weight conversion: w_qkv + w_proj -> bf16 ----------------
__global__ __launch_bounds__(256) void wconv_k(const float* __restrict__ wq,
                                               const float* __restrict__ wp,
                                               unsigned short* __restrict__ wt,
                                               unsigned short* __restrict__ wpt) {
    int i4 = blockIdx.x * 256 + threadIdx.x;   // 0..65535 float4 groups
    const float* src;
    unsigned short* dst;
    int off;
    if (i4 < 49152) { src = wq; dst = wt; off = i4 * 4; }
    else            { src = wp; dst = wpt; off = (i4 - 49152) * 4; }
    float4 v = *(const float4*)(src + off);
    ushort4 o;
    o.x = f2bf(v.x); o.y = f2bf(v.y); o.z = f2bf(v.z); o.w = f2bf(v.w);
    *(ushort4*)(dst + off) = o;
}

// ---------------- GroupNorm stats, phase A: 32 chunks per (b,g) group ----------------
__global__ __launch_bounds__(256) void gn_stats_part_k(const float* __restrict__ x,
                                                       float2* __restrict__ part) {
    int bg = blockIdx.x >> 5, ch = blockIdx.x & 31;
    const float4* base = (const float4*)(x + (size_t)bg * CPG * HW + ch * 4096);
    float s = 0.f, ss = 0.f;
    #pragma unroll
    for (int i = threadIdx.x; i < 1024; i += 256) {
        float4 v = base[i];
        s  += v.x + v.y + v.z + v.w;
        ss += v.x*v.x + v.y*v.y + v.z*v.z + v.w*v.w;
    }
    #pragma unroll
    for (int off = 32; off > 0; off >>= 1) {
        s  += __shfl_down(s, off);
        ss += __shfl_down(ss, off);
    }
    __shared__ float rs[4], rss[4];
    int wv = threadIdx.x >> 6;
    if ((threadIdx.x & 63) == 0) { rs[wv] = s; rss[wv] = ss; }
    __syncthreads();
    if (threadIdx.x == 0)
        part[blockIdx.x] = make_float2(rs[0]+rs[1]+rs[2]+rs[3], rss[0]+rss[1]+rss[2]+rss[3]);
}

// ---------------- GroupNorm stats, phase B: finalize 32 groups ----------------
__global__ __launch_bounds__(64) void gn_stats_fin_k(const float2* __restrict__ part,
                                                     float* __restrict__ stats) {
    int t = threadIdx.x;
    if (t < 32) {
        float s = 0.f, ss = 0.f;
        #pragma unroll
        for (int c = 0; c < 32; c++) { float2 v = part[t * 32 + c]; s += v.x; ss += v.y; }
        const float inv = 1.f / (float)(CPG * HW);
        float mean = s * inv;
        float var  = ss * inv - mean * mean;
        stats[2*t]   = mean;
        stats[2*t+1] = rsqrtf(var + EPS);
    }
}

// ---------------- GroupNorm apply + transpose -> ht[b][p][c] bf16 ----------------
// Block: (p-tile 64, c-tile 64, b). LDS transpose, pitch 66 ushorts (2-way max conflicts).
__global__ __launch_bounds__(256) void gn_apply_t_k(const float* __restrict__ x,
                                                    const float* __restrict__ gamma,
                                                    const float* __restrict__ beta,
                                                    const float* __restrict__ stats,
                                                    unsigned short* __restrict__ ht) {
    __shared__ unsigned short T[64 * 66];
    int b = blockIdx.z, c0 = blockIdx.y * 64, p0 = blockIdx.x * 64;
    int t = threadIdx.x;
    int cr = t >> 4, pc = t & 15;
    #pragma unroll
    for (int cp = 0; cp < 4; cp++) {
        int c = c0 + cp * 16 + cr;
        int bg = b * NG + (c >> 5);
        float mean = stats[2*bg], rstd = stats[2*bg+1];
        float sc = gamma[c] * rstd;
        float sh = beta[c] - mean * sc;
        float4 v = *(const float4*)(x + ((size_t)(b * C_ + c)) * HW + p0 + pc * 4);
        int cc = cp * 16 + cr;
        T[(pc*4 + 0) * 66 + cc] = f2bf(v.x*sc + sh);
        T[(pc*4 + 1) * 66 + cc] = f2bf(v.y*sc + sh);
        T[(pc*4 + 2) * 66 + cc] = f2bf(v.z*sc + sh);
        T[(pc*4 + 3) * 66 + cc] = f2bf(v.w*sc + sh);
    }
    __syncthreads();
    int p = t >> 2, cq = t & 3;
    const unsigned* rp = (const unsigned*)(T + p * 66 + cq * 16);
    unsigned short* dst = ht + ((size_t)b * HW + p0 + p) * 256 + c0 + cq * 16;
    *(uint4*)dst       = make_uint4(rp[0], rp[1], rp[2], rp[3]);
    *(uint4*)(dst + 8) = make_uint4(rp[4], rp[5], rp[6], rp[7]);
}

// ---------------- QKV GEMM, bf16 MFMA, LDS-free (both operands k-contiguous) ----------------
// wt[768][256] bf16; ht[b][p][256] bf16. Block = 64m x 64p, 4 waves = 2m x 2p halves.
// Epilogue per section: Q -> qt[(b,h)][p][d] (scaled), K -> kt same, V -> vv[(b,h)][d][p].
__global__ __launch_bounds__(256) void gemm_qkv_mfma_k(const unsigned short* __restrict__ wt,
                                                       const unsigned short* __restrict__ ht,
                                                       const float* __restrict__ bias,
                                                       unsigned short* __restrict__ qt,
                                                       unsigned short* __restrict__ kt,
                                                       unsigned short* __restrict__ vv) {
    int b = blockIdx.z, my = blockIdx.y, px = blockIdx.x;
    int t = threadIdx.x, wave = t >> 6, lane = t & 63, quad = lane >> 4, l16 = lane & 15;
    int mw = wave & 1, pw = wave >> 1;
    const unsigned short* Ab = wt + (size_t)(my * 64 + mw * 32) * 256;
    const unsigned short* Bb = ht + ((size_t)b * HW + px * 64 + pw * 32) * 256;
    f32x4_t acc[2][2];
    const f32x4_t zz = {0.f, 0.f, 0.f, 0.f};
    acc[0][0] = zz; acc[0][1] = zz; acc[1][0] = zz; acc[1][1] = zz;
    #pragma unroll
    for (int kc = 0; kc < 8; kc++) {
        bf16x8_t af[2], bfr[2];
        #pragma unroll
        for (int mi = 0; mi < 2; mi++)
            af[mi] = *(const bf16x8_t*)(Ab + (mi*16 + l16) * 256 + kc*32 + quad*8);
        #pragma unroll
        for (int pi = 0; pi < 2; pi++)
            bfr[pi] = *(const bf16x8_t*)(Bb + (size_t)(pi*16 + l16) * 256 + kc*32 + quad*8);
        #pragma unroll
        for (int mi = 0; mi < 2; mi++)
            #pragma unroll
            for (int pi = 0; pi < 2; pi++)
                acc[mi][pi] = __builtin_amdgcn_mfma_f32_16x16x32_bf16(af[mi], bfr[pi], acc[mi][pi], 0, 0, 0);
    }
    int sec = my >> 2, hh = my & 3;
    if (sec < 2) {
        float scl = (sec == 0) ? QSCALE : 1.f;
        unsigned short* dst = ((sec == 0) ? qt : kt) + (size_t)(b * NH + hh) * HW * 64;
        #pragma unroll
        for (int mi = 0; mi < 2; mi++) {
            int d0 = mw*32 + mi*16 + quad*4;
            #pragma unroll
            for (int pi = 0; pi < 2; pi++) {
                int p = px*64 + pw*32 + pi*16 + l16;
                ushort4 o;
                o.x = f2bf((acc[mi][pi][0] + bias[my*64 + d0 + 0]) * scl);
                o.y = f2bf((acc[mi][pi][1] + bias[my*64 + d0 + 1]) * scl);
                o.z = f2bf((acc[mi][pi][2] + bias[my*64 + d0 + 2]) * scl);
                o.w = f2bf((acc[mi][pi][3] + bias[my*64 + d0 + 3]) * scl);
                *(ushort4*)(dst + (size_t)p * 64 + d0) = o;
            }
        }
    } else {
        unsigned short* dst = vv + (size_t)(b * NH + hh) * 64 * HW;
        #pragma unroll
        for (int mi = 0; mi < 2; mi++)
            #pragma unroll
            for (int pi = 0; pi < 2; pi++) {
                int p = px*64 + pw*32 + pi*16 + l16;
                #pragma unroll
                for (int r = 0; r < 4; r++) {
                    int d = mw*32 + mi*16 + quad*4 + r;
                    dst[(size_t)d * HW + p] = f2bf(acc[mi][pi][r] + bias[my*64 + d]);
                }
            }
    }
}

// ---------------- proj GEMM, bf16 MFMA, LDS-free; + bias + residual, fp32 out ----------------
__global__ __launch_bounds__(256) void gemm_proj_mfma_k(const unsigned short* __restrict__ wpt,
                                                        const unsigned short* __restrict__ ao,
                                                        const float* __restrict__ bias,
                                                        const float* __restrict__ x,
                                                        float* __restrict__ out) {
    int b = blockIdx.z, my = blockIdx.y, px = blockIdx.x;
    int t = threadIdx.x, wave = t >> 6, lane = t & 63, quad = lane >> 4, l16 = lane & 15;
    int mw = wave & 1, pw = wave >> 1;
    const unsigned short* Ab = wpt + (size_t)(my * 64 + mw * 32) * 256;
    const unsigned short* Bb = ao + ((size_t)b * HW + px * 64 + pw * 32) * 256;
    f32x4_t acc[2][2];
    const f32x4_t zz = {0.f, 0.f, 0.f, 0.f};
    acc[0][0] = zz; acc[0][1] = zz; acc[1][0] = zz; acc[1][1] = zz;
    #pragma unroll
    for (int kc = 0; kc < 8; kc++) {
        bf16x8_t af[2], bfr[2];
        #pragma unroll
        for (int mi = 0; mi < 2; mi++)
            af[mi] = *(const bf16x8_t*)(Ab + (mi*16 + l16) * 256 + kc*32 + quad*8);
        #pragma unroll
        for (int pi = 0; pi < 2; pi++)
            bfr[pi] = *(const bf16x8_t*)(Bb + (size_t)(pi*16 + l16) * 256 + kc*32 + quad*8);
        #pragma unroll
        for (int mi = 0; mi < 2; mi++)
            #pragma unroll
            for (int pi = 0; pi < 2; pi++)
                acc[mi][pi] = __builtin_amdgcn_mfma_f32_16x16x32_bf16(af[mi], bfr[pi], acc[mi][pi], 0, 0, 0);
    }
    #pragma unroll
    for (int mi = 0; mi < 2; mi++)
        #pragma unroll
        for (int pi = 0; pi < 2; pi++) {
            int p = px*64 + pw*32 + pi*16 + l16;
            #pragma unroll
            for (int r = 0; r < 4; r++) {
                int m = my*64 + mw*32 + mi*16 + quad*4 + r;
                size_t off = (size_t)(b * C_ + m) * HW + p;
                out[off] = acc[mi][pi][r] + bias[m] + x[off];
            }
        }
}

// ---------------- Flash attention, bf16 MFMA, i×j wave split, async-staged ----------------
// qt,kt: [(b,h)][p][64] bf16 (Q pre-scaled by QSCALE); vv: [(b,h)][64][p] bf16.
// K-loop identical to r8 (158us, zero spills). Epilogue: BOTH j-halves route O^T
// through LDS (pitch-65 [i][d] layout), merged with split-k rescale, emitted as
// bf16 ao[b][p][c=h*64+d] — the proj GEMM's B-operand layout (fuses the fp32
// attno round-trip away).
__global__ __launch_bounds__(256) __attribute__((amdgpu_waves_per_eu(2, 4)))
void attn_k(const unsigned short* __restrict__ qt,
            const unsigned short* __restrict__ kt,
            const unsigned short* __restrict__ vv,
            unsigned short* __restrict__ ao) {
    // ushort idx: K0 0..4095 | K1 4096..8191 | V0 8192..12287 | V1 12288..16383 | Pt 16384..20479
    __shared__ __align__(16) unsigned short smem[20480];  // 40KB
    unsigned short* Pt = smem + 16384;
    int t = threadIdx.x;
    int wave = t >> 6, lane = t & 63, quad = lane >> 4, l16 = lane & 15;
    int iw = wave & 1, jw = wave >> 1;
    int i0 = blockIdx.x * 64;
    int hh = blockIdx.y, b = blockIdx.z;
    const unsigned short* qb = qt + (size_t)(b * NH + hh) * HW * 64;
    const char* kbp = (const char*)(kt + (size_t)(b * NH + hh) * HW * 64);
    const char* vbp = (const char*)(vv + (size_t)(b * NH + hh) * 64 * HW);

    bf16x8_t qf[2][2];
    #pragma unroll
    for (int mi = 0; mi < 2; mi++)
        #pragma unroll
        for (int kc = 0; kc < 2; kc++)
            qf[mi][kc] = *(const bf16x8_t*)(qb + (size_t)(i0 + iw * 32 + mi * 16 + l16) * 64 + kc * 32 + quad * 8);

    f32x4_t oacc[4][2];
    const f32x4_t zz = {0.f, 0.f, 0.f, 0.f};
    #pragma unroll
    for (int dt = 0; dt < 4; dt++) { oacc[dt][0] = zz; oacc[dt][1] = zz; }
    float m_pr[2] = {-INFINITY, -INFINITY};
    float l_sum[2] = {0.f, 0.f};

    int soffK[2], soffV[2], ldsoff[2];
    #pragma unroll
    for (int n = 0; n < 2; n++) {
        int s = n * 256 + t;
        int row = s >> 3;
        int c = (s & 7) ^ (row & 7);
        soffK[n] = row * 128 + c * 16;          // bytes (row=j, 128B rows)
        soffV[n] = row * (HW * 2) + c * 16;     // bytes (row=d, stride HW*2)
        ldsoff[n] = n * 2048 + wave * 512;      // ushort idx, wave-uniform
    }

    #pragma unroll
    for (int n = 0; n < 2; n++) {
        __builtin_amdgcn_global_load_lds((g_void*)(kbp + soffK[n]), (l_void*)(smem + ldsoff[n]), 16, 0, 0);
        __builtin_amdgcn_global_load_lds((g_void*)(vbp + soffV[n]), (l_void*)(smem + 8192 + ldsoff[n]), 16, 0, 0);
    }

    for (int jt = 0; jt < 64; jt++) {
        asm volatile("s_waitcnt vmcnt(0)" ::: "memory");
        asm volatile("s_barrier" ::: "memory");
        if (jt < 63) {
            const char* kb = kbp + (size_t)(jt + 1) * 8192;
            const char* vb = vbp + (size_t)(jt + 1) * 128;
            int bb = ((jt + 1) & 1) * 4096;
            #pragma unroll
            for (int n = 0; n < 2; n++) {
                __builtin_amdgcn_global_load_lds((g_void*)(kb + soffK[n]), (l_void*)(smem + bb + ldsoff[n]), 16, 0, 0);
                __builtin_amdgcn_global_load_lds((g_void*)(vb + soffV[n]), (l_void*)(smem + 8192 + bb + ldsoff[n]), 16, 0, 0);
            }
        }
        const unsigned short* Kc = smem + (jt & 1) * 4096;
        const unsigned short* Vc = smem + 8192 + (jt & 1) * 4096;

        // ---- S^T = K·Q^T on this wave's 32 j x 32 i ----
        f32x4_t sacc[2][2];
        sacc[0][0] = zz; sacc[0][1] = zz; sacc[1][0] = zz; sacc[1][1] = zz;
        #pragma unroll
        for (int nj = 0; nj < 2; nj++) {
            int j = jw * 32 + nj * 16 + l16;
            int rb = j * 8;
            bf16x8_t kf0 = *(const bf16x8_t*)&Kc[(rb + ((quad    ) ^ (j & 7))) * 8];
            bf16x8_t kf1 = *(const bf16x8_t*)&Kc[(rb + ((4 + quad) ^ (j & 7))) * 8];
            #pragma unroll
            for (int mi = 0; mi < 2; mi++) {
                sacc[mi][nj] = __builtin_amdgcn_mfma_f32_16x16x32_bf16(kf0, qf[mi][0], sacc[mi][nj], 0, 0, 0);
                sacc[mi][nj] = __builtin_amdgcn_mfma_f32_16x16x32_bf16(kf1, qf[mi][1], sacc[mi][nj], 0, 0, 0);
            }
        }

        // ---- online softmax (base-2) per i-tile; per-lane-replicated, j-half-local ----
        float alpha_[2];
        #pragma unroll
        for (int mi = 0; mi < 2; mi++) {
            float m = sacc[mi][0][0];
            #pragma unroll
            for (int nj = 0; nj < 2; nj++)
                #pragma unroll
                for (int r = 0; r < 4; r++) m = fmaxf(m, sacc[mi][nj][r]);
            m = fmaxf(m, __shfl_xor(m, 16));
            m = fmaxf(m, __shfl_xor(m, 32));
            float mnew = fmaxf(m_pr[mi], m);
            float a = __builtin_amdgcn_exp2f(m_pr[mi] - mnew);
            alpha_[mi] = a;
            float rs = 0.f;
            #pragma unroll
            for (int nj = 0; nj < 2; nj++)
                #pragma unroll
                for (int r = 0; r < 4; r++) {
                    float p = __builtin_amdgcn_exp2f(sacc[mi][nj][r] - mnew);
                    sacc[mi][nj][r] = p;
                    rs += p;
                }
            rs += __shfl_xor(rs, 16);
            rs += __shfl_xor(rs, 32);
            l_sum[mi] = l_sum[mi] * a + rs;
            m_pr[mi] = mnew;

            #pragma unroll
            for (int nj = 0; nj < 2; nj++) {
                unsigned lo = (unsigned)f2bf(sacc[mi][nj][0]) | ((unsigned)f2bf(sacc[mi][nj][1]) << 16);
                unsigned hi = (unsigned)f2bf(sacc[mi][nj][2]) | ((unsigned)f2bf(sacc[mi][nj][3]) << 16);
                int chunk = (nj * 2 + (quad >> 1)) * 16 + l16;
                *(uint2*)&Pt[((wave * 2 + mi) * 64 + chunk) * 8 + 4 * (quad & 1)] = make_uint2(lo, hi);
            }
        }

        #pragma unroll
        for (int dt = 0; dt < 4; dt++) { oacc[dt][0] *= alpha_[0]; oacc[dt][1] *= alpha_[1]; }

        asm volatile("" ::: "memory");   // wave-private P round-trip: compiler fence (r2/r7)

        bf16x8_t pf[2];
        pf[0] = *(const bf16x8_t*)&Pt[((wave * 2 + 0) * 64 + quad * 16 + l16) * 8];
        pf[1] = *(const bf16x8_t*)&Pt[((wave * 2 + 1) * 64 + quad * 16 + l16) * 8];
        #pragma unroll
        for (int dt = 0; dt < 4; dt++) {
            int d = dt * 16 + l16;
            bf16x8_t vf = *(const bf16x8_t*)&Vc[(d * 8 + ((jw * 4 + quad) ^ (d & 7))) * 8];
            oacc[dt][0] = __builtin_amdgcn_mfma_f32_16x16x32_bf16(vf, pf[0], oacc[dt][0], 0, 0, 0);
            oacc[dt][1] = __builtin_amdgcn_mfma_f32_16x16x32_bf16(vf, pf[1], oacc[dt][1], 0, 0, 0);
        }
    }

    // ---- epilogue: all waves stage O^T + (m,l) in LDS; merge j-halves; bf16 [p][c] out ----
    __syncthreads();                           // all K/V/P consumption done; reuse smem
    float* Obuf = (float*)smem;                // [(iw*2+jw)*32 + i'][65] (d fast), 33280B
    float2* ml  = (float2*)(Obuf + 4 * 32 * 65);  // 128 entries, after Obuf
    int rowbase = (iw * 2 + jw) * 32;
    #pragma unroll
    for (int dt = 0; dt < 4; dt++)
        #pragma unroll
        for (int ni = 0; ni < 2; ni++)
            #pragma unroll
            for (int r = 0; r < 4; r++)
                Obuf[(rowbase + ni * 16 + l16) * 65 + dt * 16 + quad * 4 + r] = oacc[dt][ni][r];
    if (quad == 0) {
        ml[rowbase + l16]      = make_float2(m_pr[0], l_sum[0]);
        ml[rowbase + 16 + l16] = make_float2(m_pr[1], l_sum[1]);
    }
    __syncthreads();
    {
        int iloc = t >> 2, cq = t & 3;
        int iw2 = iloc >> 5, ip = iloc & 31;
        int row0 = (iw2 * 2 + 0) * 32 + ip;
        int row1 = (iw2 * 2 + 1) * 32 + ip;
        const float* r0 = Obuf + row0 * 65;
        const float* r1 = Obuf + row1 * 65;
        float2 s0 = ml[row0], s1 = ml[row1];
        float mm = fmaxf(s0.x, s1.x);
        float a0 = __builtin_amdgcn_exp2f(s0.x - mm);
        float a1 = __builtin_amdgcn_exp2f(s1.x - mm);
        float l  = s0.y * a0 + s1.y * a1;
        float c0 = a0 / l, c1 = a1 / l;
        unsigned pk[8];
        #pragma unroll
        for (int jj = 0; jj < 8; jj++) {
            float v0 = r0[cq * 16 + 2*jj    ] * c0 + r1[cq * 16 + 2*jj    ] * c1;
            float v1 = r0[cq * 16 + 2*jj + 1] * c0 + r1[cq * 16 + 2*jj + 1] * c1;
            pk[jj] = (unsigned)f2bf(v0) | ((unsigned)f2bf(v1) << 16);
        }
        unsigned short* dst = ao + ((size_t)b * HW + i0 + iloc) * 256 + hh * 64 + cq * 16;
        *(uint4*)dst       = make_uint4(pk[0], pk[1], pk[2], pk[3]);
        *(uint4*)(dst + 8) = make_uint4(pk[4], pk[5], pk[6], pk[7]);
    }
}

extern "C" void kernel_launch(void* const* d_in, const int* in_sizes, int n_in,
                              void* d_out, int out_size, void* d_ws, size_t ws_size,
                              hipStream_t stream) {
    const float* x      = (const float*)d_in[0];
    const float* gamma  = (const float*)d_in[1];
    const float* beta   = (const float*)d_in[2];
    const float* w_qkv  = (const float*)d_in[3];
    const float* b_qkv  = (const float*)d_in[4];
    const float* w_proj = (const float*)d_in[5];
    const float* b_proj = (const float*)d_in[6];
    float* out = (float*)d_out;

    // ws: stats 256f | part 1024 float2 | ht,qt,kt,vv,ao (5 x 4M ushorts = 40MB) | wt,wpt bf16
    float* stats = (float*)d_ws;
    float2* part = (float2*)(stats + 256);
    unsigned short* ht  = (unsigned short*)(stats + 256 + 2048);
    unsigned short* qt  = ht + (size_t)4194304;
    unsigned short* kt  = qt + (size_t)4194304;
    unsigned short* vv  = kt + (size_t)4194304;
    unsigned short* ao  = vv + (size_t)4194304;
    unsigned short* wt  = ao + (size_t)4194304;
    unsigned short* wpt = wt + 196608;

    wconv_k<<<256, 256, 0, stream>>>(w_qkv, w_proj, wt, wpt);
    gn_stats_part_k<<<1024, 256, 0, stream>>>(x, part);
    gn_stats_fin_k<<<1, 64, 0, stream>>>(part, stats);
    gn_apply_t_k<<<dim3(64, 4, NB), 256, 0, stream>>>(x, gamma, beta, stats, ht);
    gemm_qkv_mfma_k<<<dim3(64, 12, NB), 256, 0, stream>>>(wt, ht, b_qkv, qt, kt, vv);
    attn_k<<<dim3(64, NH, NB), 256, 0, stream>>>(qt, kt, vv, ao);
    gemm_proj_mfma_k<<<dim3(64, 4, NB), 256, 0, stream>>>(wpt, ao, b_proj, x, out);
}